// Round 7
// baseline (2139.157 us; speedup 1.0000x reference)
//
#include <hip/hip_runtime.h>
#include <hip/hip_bf16.h>
#include <stdint.h>

typedef __attribute__((ext_vector_type(4))) float f32x4;
typedef __attribute__((ext_vector_type(8))) short s16x8;
typedef __attribute__((ext_vector_type(4))) unsigned short u16x4;

#define EPSBN 1e-5f

__device__ __forceinline__ float bf2f(unsigned short u) {
  union { unsigned int i; float f; } w; w.i = ((unsigned int)u) << 16; return w.f;
}
__device__ __forceinline__ unsigned short f2bf(float f) {
  __hip_bfloat16 h = __float2bfloat16(f);   // RNE
  unsigned short u; __builtin_memcpy(&u, &h, 2); return u;
}
__device__ __forceinline__ void gld_lds16(const void* g, void* l) {
  __builtin_amdgcn_global_load_lds(
      (const __attribute__((address_space(1))) void*)(g),
      (__attribute__((address_space(3))) void*)(l), 16, 0, 0);
}

// ---------------- graph prep ----------------
__global__ void k_init_deg(unsigned* deg, int n) {
  int i = blockIdx.x * 256 + threadIdx.x;
  if (i < n) deg[i] = 1u;               // self-loop
}
__global__ void k_count(const int* __restrict__ dst, unsigned* __restrict__ deg, int E) {
  int i = blockIdx.x * 256 + threadIdx.x;
  if (i < E) atomicAdd(&deg[dst[i]], 1u);
}
// fused: dinv + per-block degree sums
__global__ void k_prep2(const unsigned* __restrict__ deg, float* __restrict__ dinv,
                        unsigned* __restrict__ bsum, int n) {
  __shared__ unsigned s[256];
  int t = threadIdx.x, i = blockIdx.x * 256 + t;
  unsigned d = (i < n) ? deg[i] : 0u;
  if (i < n) dinv[i] = rsqrtf((float)d);
  s[t] = d;
  __syncthreads();
  for (int st = 128; st > 0; st >>= 1) {
    if (t < st) s[t] += s[t + st];
    __syncthreads();
  }
  if (t == 0) bsum[blockIdx.x] = s[0];
}
__global__ void k_scan_top(const unsigned* __restrict__ bsum, unsigned* __restrict__ bpre,
                           int nb, unsigned* __restrict__ offs, int n) {
  __shared__ unsigned s[256];
  int t = threadIdx.x;
  unsigned v = (t < nb) ? bsum[t] : 0u;
  s[t] = v; __syncthreads();
  for (int d = 1; d < 256; d <<= 1) {
    unsigned a = (t >= d) ? s[t - d] : 0u;
    __syncthreads();
    s[t] += a;
    __syncthreads();
  }
  bpre[t] = s[t] - v;                    // exclusive
  if (t == 255) offs[n] = s[255];        // total = E + n
}
__global__ void k_scan_fin(const unsigned* __restrict__ deg, const unsigned* __restrict__ bpre,
                           unsigned* __restrict__ offs, unsigned* __restrict__ cur, int n) {
  __shared__ unsigned s[256];
  int t = threadIdx.x, i = blockIdx.x * 256 + t;
  unsigned v = (i < n) ? deg[i] : 0u;
  s[t] = v; __syncthreads();
  for (int d = 1; d < 256; d <<= 1) {
    unsigned a = (t >= d) ? s[t - d] : 0u;
    __syncthreads();
    s[t] += a;
    __syncthreads();
  }
  if (i < n) {
    unsigned o = bpre[blockIdx.x] + s[t] - v;
    offs[i] = o; cur[i] = o;
  }
}
__global__ void k_fill(const int* __restrict__ src, const int* __restrict__ dst,
                       unsigned* __restrict__ cur, int* __restrict__ adj, int E, int n) {
  int i = blockIdx.x * 256 + threadIdx.x;
  int s, d;
  if (i < E)          { s = src[i]; d = dst[i]; }
  else if (i < E + n) { s = d = i - E; }        // self-loop
  else return;
  unsigned p = atomicAdd(&cur[d], 1u);
  adj[p] = s;
}
// wave-per-node bitonic sort by src + emit packed (src<<16 | bf16(w))
__global__ __launch_bounds__(256) void k_sortw(const unsigned* __restrict__ offs,
                                               const int* __restrict__ adj,
                                               const float* __restrict__ dinv,
                                               unsigned* __restrict__ ewp, int nN) {
  int wv = (blockIdx.x * 256 + threadIdx.x) >> 6;
  int lane = threadIdx.x & 63;
  if (wv >= nN) return;
  unsigned beg = offs[wv], end = offs[wv + 1];
  int len = (int)(end - beg);
  float dv = dinv[wv];
  if (len <= 64) {
    int k = (lane < len) ? adj[beg + lane] : 0x7FFFFFFF;
#pragma unroll
    for (int size = 2; size <= 64; size <<= 1) {
#pragma unroll
      for (int stride = size >> 1; stride > 0; stride >>= 1) {
        int other = __shfl_xor(k, stride);
        bool up = (lane & size) == 0;
        bool lower = (lane & stride) == 0;
        k = (lower == up) ? min(k, other) : max(k, other);
      }
    }
    if (lane < len)
      ewp[beg + lane] = ((unsigned)k << 16) | (unsigned)f2bf(dinv[k] * dv);
  } else {
    // rare fallback: unsorted (still correct: band cursor consumes prefix-wise)
    for (unsigned e = beg + lane; e < end; e += 64) {
      int s = adj[e];
      ewp[e] = ((unsigned)s << 16) | (unsigned)f2bf(dinv[s] * dv);
    }
  }
}
// all three weight transposes in one launch. W [K][N] fp32 -> Wt [Npad][K] bf16
__global__ void k_wt3(const float* __restrict__ W1, unsigned short* __restrict__ Wt1,
                      const float* __restrict__ W2, unsigned short* __restrict__ Wt2,
                      const float* __restrict__ W3, unsigned short* __restrict__ Wt3) {
  const int n1 = 256 * 1280, n2 = 256 * 256, n3 = 512 * 256;
  int idx = blockIdx.x * 256 + threadIdx.x;
  const float* W; unsigned short* Wt; int K, N;
  if (idx < n1)            { W = W1; Wt = Wt1; K = 1280; N = 256; }
  else if (idx < n1 + n2)  { W = W2; Wt = Wt2; K = 256;  N = 256; idx -= n1; }
  else if (idx < n1+n2+n3) { W = W3; Wt = Wt3; K = 256;  N = 500; idx -= n1 + n2; }
  else return;
  int nn = idx / K, k = idx - nn * K;
  float v = (nn < N) ? W[(size_t)k * N + nn] : 0.f;
  Wt[idx] = f2bf(v);
}

// ---------------- GEMM (bf16 A): C[M,N] = A[M,K] * Bt[N,K]^T ----------------
#define BM 128
#define BN 128
#define BK 64

template<int OUTF32>
__global__ __launch_bounds__(256, 4) void k_gemm(
    const unsigned short* __restrict__ Au, const unsigned short* __restrict__ Bt,
    void* __restrict__ Coutv, const float* __restrict__ bias,
    int M, int N, int K, int MT, int NT)
{
  __shared__ __align__(16) unsigned short As[BM * BK];
  __shared__ __align__(16) unsigned short Bs[BN * BK];

  int d = blockIdx.x;
  int xc = d & 7, sb = d >> 3;
  int nt = sb % NT, mt = (sb / NT) * 8 + xc;
  if (mt >= MT) return;
  int m0 = mt * BM, n0 = nt * BN;

  int tid = threadIdx.x, lane = tid & 63, wave = tid >> 6;
  int wm = wave >> 1, wn = wave & 1;
  int l15 = lane & 15, l4 = lane >> 4;

  f32x4 acc[4][4];
#pragma unroll
  for (int i = 0; i < 4; ++i)
#pragma unroll
    for (int j = 0; j < 4; ++j) acc[i][j] = 0.f;

  int srow[4], scg[4];
#pragma unroll
  for (int i = 0; i < 4; ++i) {
    int ci = (wave + 4 * i) * 64 + lane;
    srow[i] = ci >> 3;                         // 8 chunks per 128B row
    scg[i] = (ci & 7) ^ (srow[i] & 7);         // pre-swizzled source chunk
  }

  int nk = K / BK;
  for (int kt = 0; kt < nk; ++kt) {
    __syncthreads();
#pragma unroll
    for (int i = 0; i < 4; ++i) {
      int gr = m0 + srow[i]; gr = gr < M ? gr : M - 1;
      gld_lds16(Au + (size_t)gr * K + kt * BK + scg[i] * 8, As + (wave + 4 * i) * 512);
    }
#pragma unroll
    for (int i = 0; i < 4; ++i) {
      int gn = n0 + srow[i];
      gld_lds16(Bt + (size_t)gn * K + kt * BK + scg[i] * 8, Bs + (wave + 4 * i) * 512);
    }
    __syncthreads();

#pragma unroll
    for (int ks = 0; ks < 2; ++ks) {
      s16x8 af[4], bf[4];
#pragma unroll
      for (int f = 0; f < 4; ++f) {
        int r = wm * 64 + f * 16 + l15;
        int ca = (ks * 4 + l4) ^ (r & 7);
        af[f] = *(const s16x8*)(As + r * 64 + ca * 8);
        int nloc = wn * 64 + f * 16 + l15;
        int cb = (ks * 4 + l4) ^ (nloc & 7);
        bf[f] = *(const s16x8*)(Bs + nloc * 64 + cb * 8);
      }
#pragma unroll
      for (int fm = 0; fm < 4; ++fm)
#pragma unroll
        for (int fn = 0; fn < 4; ++fn)
          acc[fm][fn] = __builtin_amdgcn_mfma_f32_16x16x32_bf16(af[fm], bf[fn], acc[fm][fn], 0, 0, 0);
    }
  }

#pragma unroll
  for (int fm = 0; fm < 4; ++fm) {
#pragma unroll
    for (int fn = 0; fn < 4; ++fn) {
#pragma unroll
      for (int r = 0; r < 4; ++r) {
        int row = m0 + wm * 64 + fm * 16 + l4 * 4 + r;
        int col = n0 + wn * 64 + fn * 16 + l15;
        if (row < M && col < N) {
          if (OUTF32)
            ((float*)Coutv)[(size_t)row * N + col] = acc[fm][fn][r] + bias[col];
          else
            ((unsigned short*)Coutv)[(size_t)row * N + col] = f2bf(acc[fm][fn][r]);
        }
      }
    }
  }
}

// ------- GEMM layer1: A fp32 row-major via global_load_lds, cvt at frag read -------
__global__ __launch_bounds__(256, 3) void k_gemmF(
    const float* __restrict__ Af, const unsigned short* __restrict__ Bt,
    unsigned short* __restrict__ Cout, int M, int N, int K, int MT, int NT)
{
  __shared__ __align__(16) float As[BM * BK];           // 32 KB fp32
  __shared__ __align__(16) unsigned short Bs[BN * BK];  // 16 KB

  int d = blockIdx.x;
  int xc = d & 7, sb = d >> 3;
  int nt = sb % NT, mt = (sb / NT) * 8 + xc;
  if (mt >= MT) return;
  int m0 = mt * BM, n0 = nt * BN;

  int tid = threadIdx.x, lane = tid & 63, wave = tid >> 6;
  int wm = wave >> 1, wn = wave & 1;
  int l15 = lane & 15, l4 = lane >> 4;

  f32x4 acc[4][4];
#pragma unroll
  for (int i = 0; i < 4; ++i)
#pragma unroll
    for (int j = 0; j < 4; ++j) acc[i][j] = 0.f;

  int arow[8], acs[8];
#pragma unroll
  for (int i = 0; i < 8; ++i) {
    int ci = (i * 4 + wave) * 64 + lane;
    arow[i] = ci >> 4;
    acs[i] = (ci & 15) ^ ((arow[i] & 7) << 1);  // pre-swizzled (pair-preserving)
  }
  int brow[4], bcg[4];
#pragma unroll
  for (int i = 0; i < 4; ++i) {
    int ci = (i * 4 + wave) * 64 + lane;
    brow[i] = ci >> 3;
    bcg[i] = (ci & 7) ^ (brow[i] & 7);
  }

  int nk = K / BK;
  for (int kt = 0; kt < nk; ++kt) {
    __syncthreads();
#pragma unroll
    for (int i = 0; i < 8; ++i) {
      int gr = m0 + arow[i]; gr = gr < M ? gr : M - 1;
      gld_lds16(Af + (size_t)gr * K + kt * BK + acs[i] * 4, As + (i * 4 + wave) * 256);
    }
#pragma unroll
    for (int i = 0; i < 4; ++i) {
      int gn = n0 + brow[i];
      gld_lds16(Bt + (size_t)gn * K + kt * BK + bcg[i] * 8, Bs + (i * 4 + wave) * 512);
    }
    __syncthreads();

#pragma unroll
    for (int ks = 0; ks < 2; ++ks) {
      s16x8 af[4], bf[4];
#pragma unroll
      for (int f = 0; f < 4; ++f) {
        int r = wm * 64 + f * 16 + l15;
        int c0 = (2 * (ks * 4 + l4)) ^ ((r & 7) << 1);
        f32x4 a0 = *(const f32x4*)(As + r * 64 + c0 * 4);
        f32x4 a1 = *(const f32x4*)(As + r * 64 + c0 * 4 + 4);
        s16x8 pk;
        pk[0] = (short)f2bf(a0[0]); pk[1] = (short)f2bf(a0[1]);
        pk[2] = (short)f2bf(a0[2]); pk[3] = (short)f2bf(a0[3]);
        pk[4] = (short)f2bf(a1[0]); pk[5] = (short)f2bf(a1[1]);
        pk[6] = (short)f2bf(a1[2]); pk[7] = (short)f2bf(a1[3]);
        af[f] = pk;
        int nloc = wn * 64 + f * 16 + l15;
        int cb = (ks * 4 + l4) ^ (nloc & 7);
        bf[f] = *(const s16x8*)(Bs + nloc * 64 + cb * 8);
      }
#pragma unroll
      for (int fm = 0; fm < 4; ++fm)
#pragma unroll
        for (int fn = 0; fn < 4; ++fn)
          acc[fm][fn] = __builtin_amdgcn_mfma_f32_16x16x32_bf16(af[fm], bf[fn], acc[fm][fn], 0, 0, 0);
    }
  }

#pragma unroll
  for (int fm = 0; fm < 4; ++fm) {
#pragma unroll
    for (int fn = 0; fn < 4; ++fn) {
#pragma unroll
      for (int r = 0; r < 4; ++r) {
        int row = m0 + wm * 64 + fm * 16 + l4 * 4 + r;
        int col = n0 + wn * 64 + fn * 16 + l15;
        if (row < M && col < N)
          Cout[(size_t)row * N + col] = f2bf(acc[fm][fn][r]);
      }
    }
  }
}

// -------- banded aggregation: src swept in L2-sized bands, advisory cross-block sync --------
// grid = 1024 blocks x 256 (all co-resident at VGPR<=128); wave owns NPW=13 nodes.
#define NPW 13
#define NBAND 10

template<int BNRELU, int BIAS>
__global__ __launch_bounds__(256, 4) void k_aggb(
    const unsigned short* __restrict__ h, const unsigned* __restrict__ ewp,
    const unsigned* __restrict__ offs,
    const float* __restrict__ bias, const float* __restrict__ gam,
    const float* __restrict__ bet, const float* __restrict__ mea,
    const float* __restrict__ var,
    unsigned short* __restrict__ outp, int nN, int bandw, unsigned* __restrict__ barc)
{
  int wave = threadIdx.x >> 6, lane = threadIdx.x & 63;
  int gw = blockIdx.x * 4 + wave;          // global wave id
  int vb = gw * NPW;
  const unsigned short* hb = h + lane * 4;

  unsigned cur_[NPW], end_[NPW];
  f32x4 acc_[NPW];
#pragma unroll
  for (int n = 0; n < NPW; ++n) {
    int v = vb + n;
    cur_[n] = (v < nN) ? offs[v] : 0u;
    end_[n] = (v < nN) ? offs[v + 1] : 0u;
    acc_[n] = 0.f;
  }

  for (int b = 0; b < NBAND; ++b) {
    unsigned hi = (unsigned)(b + 1) * (unsigned)bandw;
#pragma unroll
    for (int n = 0; n < NPW; ++n) {
      while (true) {
        unsigned rem = end_[n] - cur_[n];
        if (rem == 0) break;
        unsigned pck = 0;
        if (lane < (int)rem) pck = ewp[cur_[n] + lane];
        unsigned long long mask = __ballot((lane < (int)rem) && ((pck >> 16) < hi));
        unsigned long long inv = ~mask;
        int cnt = (inv == 0ull) ? 64 : (int)__builtin_ctzll(inv);
        for (int e = 0; e < cnt; e += 4) {
          u16x4 q[4]; float ww[4];
#pragma unroll
          for (int j = 0; j < 4; ++j) {
            int idx = e + j;
            unsigned pj = __shfl((int)pck, idx & 63);
            if (idx >= cnt) pj = 0;
            ww[j] = bf2f((unsigned short)(pj & 0xffffu));
            q[j] = *(const u16x4*)(hb + (size_t)(pj >> 16) * 256);
          }
#pragma unroll
          for (int j = 0; j < 4; ++j) {
            acc_[n][0] += bf2f(q[j][0]) * ww[j];
            acc_[n][1] += bf2f(q[j][1]) * ww[j];
            acc_[n][2] += bf2f(q[j][2]) * ww[j];
            acc_[n][3] += bf2f(q[j][3]) * ww[j];
          }
        }
        cur_[n] += (unsigned)cnt;
        if (cnt < 64) break;
      }
    }
    // advisory cross-block band barrier (timing only; correctness independent)
    if (b + 1 < NBAND) {
      __syncthreads();
      if (threadIdx.x == 0) {
        __hip_atomic_fetch_add(&barc[b], 1u, __ATOMIC_RELAXED, __HIP_MEMORY_SCOPE_AGENT);
        int it = 0;
        while (__hip_atomic_load(&barc[b], __ATOMIC_RELAXED, __HIP_MEMORY_SCOPE_AGENT) < gridDim.x
               && it < 4000) {
          __builtin_amdgcn_s_sleep(2);
          ++it;
        }
      }
      __syncthreads();
    }
  }

  // epilogue: bias/BN/ReLU fused as val*sc + sh
  f32x4 sc, sh;
  if (BNRELU) {
    f32x4 bv = *(const f32x4*)(bias + lane * 4);
    f32x4 gv = *(const f32x4*)(gam + lane * 4);
    f32x4 ev = *(const f32x4*)(bet + lane * 4);
    f32x4 mv = *(const f32x4*)(mea + lane * 4);
    f32x4 vv = *(const f32x4*)(var + lane * 4);
#pragma unroll
    for (int j = 0; j < 4; ++j) {
      sc[j] = gv[j] * rsqrtf(vv[j] + EPSBN);
      sh[j] = (bv[j] - mv[j]) * sc[j] + ev[j];
    }
  }
#pragma unroll
  for (int n = 0; n < NPW; ++n) {
    int v = vb + n;
    if (v >= nN) continue;
    u16x4 o;
#pragma unroll
    for (int j = 0; j < 4; ++j) {
      float val = acc_[n][j];
      if (BNRELU) val = fmaxf(val * sc[j] + sh[j], 0.f);
      o[j] = f2bf(val);
    }
    *(u16x4*)(outp + (size_t)v * 256 + lane * 4) = o;
  }
}

// ---------------- launch ----------------
extern "C" void kernel_launch(void* const* d_in, const int* in_sizes, int n_in,
                              void* d_out, int out_size, void* d_ws, size_t ws_size,
                              hipStream_t stream) {
  const float* x   = (const float*)d_in[0];
  const int*   ei  = (const int*)d_in[1];
  const float* W1  = (const float*)d_in[2];
  const float* b1  = (const float*)d_in[3];
  const float* g1  = (const float*)d_in[4];
  const float* be1 = (const float*)d_in[5];
  const float* m1  = (const float*)d_in[6];
  const float* v1  = (const float*)d_in[7];
  const float* W2  = (const float*)d_in[8];
  const float* b2  = (const float*)d_in[9];
  const float* g2  = (const float*)d_in[10];
  const float* be2 = (const float*)d_in[11];
  const float* m2  = (const float*)d_in[12];
  const float* v2  = (const float*)d_in[13];
  const float* W3  = (const float*)d_in[14];
  const float* b3  = (const float*)d_in[15];

  const int IN = 1280, H = 256, OUT = 500, OUTP = 512;
  int E  = in_sizes[1] / 2;
  int nN = in_sizes[0] / IN;
  const int* srcI = ei;
  const int* dstI = ei + E;

  char* p = (char*)d_ws;
  auto carve = [&](size_t bytes) { char* r = p; p += (bytes + 511) & ~(size_t)511; return r; };
  unsigned short* Wt1 = (unsigned short*)carve((size_t)H * IN * 2);
  unsigned short* Wt2 = (unsigned short*)carve((size_t)H * H * 2);
  unsigned short* Wt3 = (unsigned short*)carve((size_t)OUTP * H * 2);
  unsigned* deg  = (unsigned*)carve((size_t)nN * 4);
  float*    dinv = (float*)carve((size_t)nN * 4);
  unsigned* offs = (unsigned*)carve((size_t)(nN + 1) * 4);
  unsigned* cur  = (unsigned*)carve((size_t)nN * 4);
  unsigned* bsum = (unsigned*)carve(256 * 4);
  unsigned* bpre = (unsigned*)carve(256 * 4);
  unsigned* barc = (unsigned*)carve(64 * 4);
  int*      adj  = (int*)carve((size_t)(E + nN) * 4);
  unsigned* ewp  = (unsigned*)carve((size_t)(E + nN) * 4);
  unsigned short* bufA = (unsigned short*)carve((size_t)nN * H * 2);
  unsigned short* bufB = (unsigned short*)carve((size_t)nN * H * 2);

  hipMemsetAsync(barc, 0, 64 * 4, stream);   // advisory-barrier counters

  int NB = (nN + 255) / 256;
  k_init_deg<<<NB, 256, 0, stream>>>(deg, nN);
  k_count<<<(E + 255) / 256, 256, 0, stream>>>(dstI, deg, E);
  k_prep2<<<NB, 256, 0, stream>>>(deg, dinv, bsum, nN);
  k_scan_top<<<1, 256, 0, stream>>>(bsum, bpre, NB, offs, nN);
  k_scan_fin<<<NB, 256, 0, stream>>>(deg, bpre, offs, cur, nN);
  k_fill<<<(E + nN + 255) / 256, 256, 0, stream>>>(srcI, dstI, cur, adj, E, nN);
  k_sortw<<<(nN + 3) / 4, 256, 0, stream>>>(offs, adj, dinv, ewp, nN);
  k_wt3<<<(H * IN + H * H + OUTP * H + 255) / 256, 256, 0, stream>>>(W1, Wt1, W2, Wt2, W3, Wt3);

  int MT = (nN + BM - 1) / BM;          // 391
  int mg = (MT + 7) / 8;                // 49
  int bandw = (nN + NBAND - 1) / NBAND; // 5000
  int aggGrid = (nN + NPW * 4 - 1) / (NPW * 4);   // 962 <= 1024, all co-resident

  // layer 1:  h1 = x*W1 ; act1 = BNReLU(agg(h1)+b1)
  k_gemmF<<<mg * 8 * 2, 256, 0, stream>>>(x, Wt1, bufA, nN, H, IN, MT, 2);
  k_aggb<1, 1><<<aggGrid, 256, 0, stream>>>(bufA, ewp, offs, b1, g1, be1, m1, v1,
                                            bufB, nN, bandw, barc);
  // layer 2:  h2 = act1*W2 ; act2 = BNReLU(agg(h2)+b2)
  k_gemm<0><<<mg * 8 * 2, 256, 0, stream>>>(bufB, Wt2, bufA, nullptr, nN, H, H, MT, 2);
  k_aggb<1, 1><<<aggGrid, 256, 0, stream>>>(bufA, ewp, offs, b2, g2, be2, m2, v2,
                                            bufB, nN, bandw, barc + 16);
  // layer 3 (reordered):  out = (agg(act2)) * W3 + b3
  k_aggb<0, 0><<<aggGrid, 256, 0, stream>>>(bufB, ewp, offs, nullptr, nullptr, nullptr,
                                            nullptr, nullptr, bufA, nN, bandw, barc + 32);
  k_gemm<1><<<mg * 8 * 4, 256, 0, stream>>>(bufA, Wt3, d_out, b3, nN, OUT, H, MT, 4);
}

// Round 8
// 698.766 us; speedup vs baseline: 3.0613x; 3.0613x over previous
//
#include <hip/hip_runtime.h>
#include <hip/hip_bf16.h>
#include <stdint.h>

typedef __attribute__((ext_vector_type(4))) float f32x4;
typedef __attribute__((ext_vector_type(8))) short s16x8;
typedef __attribute__((ext_vector_type(4))) unsigned short u16x4;

#define EPSBN 1e-5f

__device__ __forceinline__ float bf2f(unsigned short u) {
  union { unsigned int i; float f; } w; w.i = ((unsigned int)u) << 16; return w.f;
}
__device__ __forceinline__ unsigned short f2bf(float f) {
  __hip_bfloat16 h = __float2bfloat16(f);   // RNE
  unsigned short u; __builtin_memcpy(&u, &h, 2); return u;
}
__device__ __forceinline__ void gld_lds16(const void* g, void* l) {
  __builtin_amdgcn_global_load_lds(
      (const __attribute__((address_space(1))) void*)(g),
      (__attribute__((address_space(3))) void*)(l), 16, 0, 0);
}

// ---------------- graph prep ----------------
// deg[] holds edge-count only (memset 0 + count); effective degree = deg+1 (self-loop)
__global__ void k_count(const int* __restrict__ dst, unsigned* __restrict__ deg, int E) {
  int i = blockIdx.x * 256 + threadIdx.x;
  if (i < E) atomicAdd(&deg[dst[i]], 1u);
}
// fused: dinv + per-block (deg+1) sums
__global__ void k_prep2(const unsigned* __restrict__ deg, float* __restrict__ dinv,
                        unsigned* __restrict__ bsum, int n) {
  __shared__ unsigned s[256];
  int t = threadIdx.x, i = blockIdx.x * 256 + t;
  unsigned d = (i < n) ? deg[i] + 1u : 0u;
  if (i < n) dinv[i] = rsqrtf((float)d);
  s[t] = d;
  __syncthreads();
  for (int st = 128; st > 0; st >>= 1) {
    if (t < st) s[t] += s[t + st];
    __syncthreads();
  }
  if (t == 0) bsum[blockIdx.x] = s[0];
}
__global__ void k_scan_top(const unsigned* __restrict__ bsum, unsigned* __restrict__ bpre,
                           int nb, unsigned* __restrict__ offs, int n) {
  __shared__ unsigned s[256];
  int t = threadIdx.x;
  unsigned v = (t < nb) ? bsum[t] : 0u;
  s[t] = v; __syncthreads();
  for (int d = 1; d < 256; d <<= 1) {
    unsigned a = (t >= d) ? s[t - d] : 0u;
    __syncthreads();
    s[t] += a;
    __syncthreads();
  }
  bpre[t] = s[t] - v;                    // exclusive
  if (t == 255) offs[n] = s[255];        // total = E + n
}
__global__ void k_scan_fin(const unsigned* __restrict__ deg, const unsigned* __restrict__ bpre,
                           unsigned* __restrict__ offs, unsigned* __restrict__ cur, int n) {
  __shared__ unsigned s[256];
  int t = threadIdx.x, i = blockIdx.x * 256 + t;
  unsigned v = (i < n) ? deg[i] + 1u : 0u;
  s[t] = v; __syncthreads();
  for (int d = 1; d < 256; d <<= 1) {
    unsigned a = (t >= d) ? s[t - d] : 0u;
    __syncthreads();
    s[t] += a;
    __syncthreads();
  }
  if (i < n) {
    unsigned o = bpre[blockIdx.x] + s[t] - v;
    offs[i] = o; cur[i] = o;
  }
}
// fill CSR with u16 src ids (pre-scaled-h scheme needs no per-edge weight)
__global__ void k_fill(const int* __restrict__ src, const int* __restrict__ dst,
                       unsigned* __restrict__ cur, unsigned short* __restrict__ ewp,
                       int E, int n) {
  int i = blockIdx.x * 256 + threadIdx.x;
  int s, d;
  if (i < E)          { s = src[i]; d = dst[i]; }
  else if (i < E + n) { s = d = i - E; }        // self-loop
  else return;
  unsigned p = atomicAdd(&cur[d], 1u);
  ewp[p] = (unsigned short)s;
}
// wave-per-node in-place bitonic sort of u16 src lists (L2 sweep locality)
__global__ __launch_bounds__(256) void k_sortw(const unsigned* __restrict__ offs,
                                               unsigned short* __restrict__ ewp, int nN) {
  int wv = (blockIdx.x * 256 + threadIdx.x) >> 6;
  int lane = threadIdx.x & 63;
  if (wv >= nN) return;
  unsigned beg = offs[wv], end = offs[wv + 1];
  int len = (int)(end - beg);
  if (len > 64) return;                  // rare: leave unsorted (correct, minor locality loss)
  int k = (lane < len) ? (int)ewp[beg + lane] : 0x10000;
#pragma unroll
  for (int size = 2; size <= 64; size <<= 1) {
#pragma unroll
    for (int stride = size >> 1; stride > 0; stride >>= 1) {
      int other = __shfl_xor(k, stride);
      bool up = (lane & size) == 0;
      bool lower = (lane & stride) == 0;
      k = (lower == up) ? min(k, other) : max(k, other);
    }
  }
  if (lane < len) ewp[beg + lane] = (unsigned short)k;
}
// weight transposes (fp32 [K][N] -> bf16 [Npad][K]) + zero pad-row nN of both h buffers
__global__ void k_wt3(const float* __restrict__ W1, unsigned short* __restrict__ Wt1,
                      const float* __restrict__ W2, unsigned short* __restrict__ Wt2,
                      const float* __restrict__ W3, unsigned short* __restrict__ Wt3,
                      unsigned short* __restrict__ bufA, unsigned short* __restrict__ bufB,
                      int nN) {
  const int n1 = 256 * 1280, n2 = 256 * 256, n3 = 512 * 256;
  int idx = blockIdx.x * 256 + threadIdx.x;
  if (idx >= n1 + n2 + n3) {
    int z = idx - (n1 + n2 + n3);
    if (z < 256)      bufA[(size_t)nN * 256 + z] = 0;
    else if (z < 512) bufB[(size_t)nN * 256 + (z - 256)] = 0;
    return;
  }
  const float* W; unsigned short* Wt; int K, N;
  if (idx < n1)           { W = W1; Wt = Wt1; K = 1280; N = 256; }
  else if (idx < n1 + n2) { W = W2; Wt = Wt2; K = 256;  N = 256; idx -= n1; }
  else                    { W = W3; Wt = Wt3; K = 256;  N = 500; idx -= n1 + n2; }
  int nn = idx / K, k = idx - nn * K;
  float v = (nn < N) ? W[(size_t)k * N + nn] : 0.f;
  Wt[idx] = f2bf(v);
}

// ---------------- GEMM (bf16 A): C[M,N] = A[M,K] * Bt[N,K]^T ----------------
// OUTMODE 0: bf16, value*dinv[row] (feeds an aggregation); 1: fp32 + bias (final out)
#define BM 128
#define BN 128
#define BK 64

template<int OUTMODE>
__global__ __launch_bounds__(256, 4) void k_gemm(
    const unsigned short* __restrict__ Au, const unsigned short* __restrict__ Bt,
    void* __restrict__ Coutv, const float* __restrict__ bias,
    const float* __restrict__ dinv, int M, int N, int K, int MT, int NT)
{
  __shared__ __align__(16) unsigned short As[BM * BK];
  __shared__ __align__(16) unsigned short Bs[BN * BK];

  int d = blockIdx.x;
  int xc = d & 7, sb = d >> 3;
  int nt = sb % NT, mt = (sb / NT) * 8 + xc;
  if (mt >= MT) return;
  int m0 = mt * BM, n0 = nt * BN;

  int tid = threadIdx.x, lane = tid & 63, wave = tid >> 6;
  int wm = wave >> 1, wn = wave & 1;
  int l15 = lane & 15, l4 = lane >> 4;

  f32x4 acc[4][4];
#pragma unroll
  for (int i = 0; i < 4; ++i)
#pragma unroll
    for (int j = 0; j < 4; ++j) acc[i][j] = 0.f;

  int srow[4], scg[4];
#pragma unroll
  for (int i = 0; i < 4; ++i) {
    int ci = (wave + 4 * i) * 64 + lane;
    srow[i] = ci >> 3;                         // 8 chunks per 128B row
    scg[i] = (ci & 7) ^ (srow[i] & 7);         // pre-swizzled source chunk
  }

  int nk = K / BK;
  for (int kt = 0; kt < nk; ++kt) {
    __syncthreads();
#pragma unroll
    for (int i = 0; i < 4; ++i) {
      int gr = m0 + srow[i]; gr = gr < M ? gr : M - 1;
      gld_lds16(Au + (size_t)gr * K + kt * BK + scg[i] * 8, As + (wave + 4 * i) * 512);
    }
#pragma unroll
    for (int i = 0; i < 4; ++i) {
      int gn = n0 + srow[i];
      gld_lds16(Bt + (size_t)gn * K + kt * BK + scg[i] * 8, Bs + (wave + 4 * i) * 512);
    }
    __syncthreads();

#pragma unroll
    for (int ks = 0; ks < 2; ++ks) {
      s16x8 af[4], bf[4];
#pragma unroll
      for (int f = 0; f < 4; ++f) {
        int r = wm * 64 + f * 16 + l15;
        int ca = (ks * 4 + l4) ^ (r & 7);
        af[f] = *(const s16x8*)(As + r * 64 + ca * 8);
        int nloc = wn * 64 + f * 16 + l15;
        int cb = (ks * 4 + l4) ^ (nloc & 7);
        bf[f] = *(const s16x8*)(Bs + nloc * 64 + cb * 8);
      }
#pragma unroll
      for (int fm = 0; fm < 4; ++fm)
#pragma unroll
        for (int fn = 0; fn < 4; ++fn)
          acc[fm][fn] = __builtin_amdgcn_mfma_f32_16x16x32_bf16(af[fm], bf[fn], acc[fm][fn], 0, 0, 0);
    }
  }

#pragma unroll
  for (int fm = 0; fm < 4; ++fm) {
#pragma unroll
    for (int r = 0; r < 4; ++r) {
      int row = m0 + wm * 64 + fm * 16 + l4 * 4 + r;
      float dsc = (OUTMODE == 0 && row < M) ? dinv[row] : 0.f;
#pragma unroll
      for (int fn = 0; fn < 4; ++fn) {
        int col = n0 + wn * 64 + fn * 16 + l15;
        if (row < M && col < N) {
          if (OUTMODE == 1)
            ((float*)Coutv)[(size_t)row * N + col] = acc[fm][fn][r] + bias[col];
          else
            ((unsigned short*)Coutv)[(size_t)row * N + col] = f2bf(acc[fm][fn][r] * dsc);
        }
      }
    }
  }
}

// ------- GEMM layer1: A fp32 row-major via global_load_lds, cvt at frag read; out bf16*dinv -------
__global__ __launch_bounds__(256, 3) void k_gemmF(
    const float* __restrict__ Af, const unsigned short* __restrict__ Bt,
    unsigned short* __restrict__ Cout, const float* __restrict__ dinv,
    int M, int N, int K, int MT, int NT)
{
  __shared__ __align__(16) float As[BM * BK];           // 32 KB fp32
  __shared__ __align__(16) unsigned short Bs[BN * BK];  // 16 KB

  int d = blockIdx.x;
  int xc = d & 7, sb = d >> 3;
  int nt = sb % NT, mt = (sb / NT) * 8 + xc;
  if (mt >= MT) return;
  int m0 = mt * BM, n0 = nt * BN;

  int tid = threadIdx.x, lane = tid & 63, wave = tid >> 6;
  int wm = wave >> 1, wn = wave & 1;
  int l15 = lane & 15, l4 = lane >> 4;

  f32x4 acc[4][4];
#pragma unroll
  for (int i = 0; i < 4; ++i)
#pragma unroll
    for (int j = 0; j < 4; ++j) acc[i][j] = 0.f;

  int arow[8], acs[8];
#pragma unroll
  for (int i = 0; i < 8; ++i) {
    int ci = (i * 4 + wave) * 64 + lane;
    arow[i] = ci >> 4;
    acs[i] = (ci & 15) ^ ((arow[i] & 7) << 1);  // pre-swizzled (pair-preserving)
  }
  int brow[4], bcg[4];
#pragma unroll
  for (int i = 0; i < 4; ++i) {
    int ci = (i * 4 + wave) * 64 + lane;
    brow[i] = ci >> 3;
    bcg[i] = (ci & 7) ^ (brow[i] & 7);
  }

  int nk = K / BK;
  for (int kt = 0; kt < nk; ++kt) {
    __syncthreads();
#pragma unroll
    for (int i = 0; i < 8; ++i) {
      int gr = m0 + arow[i]; gr = gr < M ? gr : M - 1;
      gld_lds16(Af + (size_t)gr * K + kt * BK + acs[i] * 4, As + (i * 4 + wave) * 256);
    }
#pragma unroll
    for (int i = 0; i < 4; ++i) {
      int gn = n0 + brow[i];
      gld_lds16(Bt + (size_t)gn * K + kt * BK + bcg[i] * 8, Bs + (i * 4 + wave) * 512);
    }
    __syncthreads();

#pragma unroll
    for (int ks = 0; ks < 2; ++ks) {
      s16x8 af[4], bf[4];
#pragma unroll
      for (int f = 0; f < 4; ++f) {
        int r = wm * 64 + f * 16 + l15;
        int c0 = (2 * (ks * 4 + l4)) ^ ((r & 7) << 1);
        f32x4 a0 = *(const f32x4*)(As + r * 64 + c0 * 4);
        f32x4 a1 = *(const f32x4*)(As + r * 64 + c0 * 4 + 4);
        s16x8 pk;
        pk[0] = (short)f2bf(a0[0]); pk[1] = (short)f2bf(a0[1]);
        pk[2] = (short)f2bf(a0[2]); pk[3] = (short)f2bf(a0[3]);
        pk[4] = (short)f2bf(a1[0]); pk[5] = (short)f2bf(a1[1]);
        pk[6] = (short)f2bf(a1[2]); pk[7] = (short)f2bf(a1[3]);
        af[f] = pk;
        int nloc = wn * 64 + f * 16 + l15;
        int cb = (ks * 4 + l4) ^ (nloc & 7);
        bf[f] = *(const s16x8*)(Bs + nloc * 64 + cb * 8);
      }
#pragma unroll
      for (int fm = 0; fm < 4; ++fm)
#pragma unroll
        for (int fn = 0; fn < 4; ++fn)
          acc[fm][fn] = __builtin_amdgcn_mfma_f32_16x16x32_bf16(af[fm], bf[fn], acc[fm][fn], 0, 0, 0);
    }
  }

#pragma unroll
  for (int fm = 0; fm < 4; ++fm) {
#pragma unroll
    for (int r = 0; r < 4; ++r) {
      int row = m0 + wm * 64 + fm * 16 + l4 * 4 + r;
      float dsc = (row < M) ? dinv[row] : 0.f;
#pragma unroll
      for (int fn = 0; fn < 4; ++fn) {
        int col = n0 + wn * 64 + fn * 16 + l15;
        if (row < M && col < N)
          Cout[(size_t)row * N + col] = f2bf(acc[fm][fn][r] * dsc);
      }
    }
  }
}

// -------- aggregation (C=256), 16-deep pipelined row gathers, pre-scaled h (no weights) --------
// h rows are h'=h*dinv[src]; pad slots gather zero-row nN. Result *= dinv[v] in epilogue.
template<int BNRELU, int SCALEOUT>
__global__ __launch_bounds__(256) void k_agg(
    const unsigned short* __restrict__ h, const unsigned short* __restrict__ ewp,
    const unsigned* __restrict__ offs, const float* __restrict__ dinv,
    const float* __restrict__ bias, const float* __restrict__ gam,
    const float* __restrict__ bet, const float* __restrict__ mea,
    const float* __restrict__ var, unsigned short* __restrict__ outp, int nN)
{
  int wave = threadIdx.x >> 6, lane = threadIdx.x & 63;
  int v = blockIdx.x * 4 + wave;
  if (v >= nN) return;
  unsigned beg = offs[v], end = offs[v + 1];
  int len = (int)(end - beg);
  float dv = dinv[v];
  const unsigned short* hb = h + lane * 4;
  float a0 = 0, a1 = 0, a2 = 0, a3 = 0;

  for (int base = 0; base < len; base += 64) {
    int m = min(64, len - base);
    int myp = (lane < m) ? (int)ewp[beg + base + lane] : nN;   // pad -> zero row
    int ng = (m + 15) >> 4;

    u16x4 q[16];
#pragma unroll
    for (int r = 0; r < 16; ++r) {
      int s = __shfl(myp, r);
      q[r] = *(const u16x4*)(hb + (size_t)s * 256);
    }
    for (int g = 1; g < ng; ++g) {
      u16x4 q2[16];
#pragma unroll
      for (int r = 0; r < 16; ++r) {
        int s = __shfl(myp, g * 16 + r);
        q2[r] = *(const u16x4*)(hb + (size_t)s * 256);
      }
#pragma unroll
      for (int r = 0; r < 16; ++r) {
        a0 += bf2f(q[r][0]); a1 += bf2f(q[r][1]);
        a2 += bf2f(q[r][2]); a3 += bf2f(q[r][3]);
      }
#pragma unroll
      for (int r = 0; r < 16; ++r) q[r] = q2[r];
    }
#pragma unroll
    for (int r = 0; r < 16; ++r) {
      a0 += bf2f(q[r][0]); a1 += bf2f(q[r][1]);
      a2 += bf2f(q[r][2]); a3 += bf2f(q[r][3]);
    }
  }

  float va[4] = {a0, a1, a2, a3};
  int ch0 = lane * 4;
#pragma unroll
  for (int j = 0; j < 4; ++j) {
    int ch = ch0 + j;
    float val = va[j] * dv;                    // dst-side norm factor
    if (BNRELU) {
      val += bias[ch];
      val = (val - mea[ch]) * rsqrtf(var[ch] + EPSBN) * gam[ch] + bet[ch];
      val = fmaxf(val, 0.f);
    }
    if (SCALEOUT) val *= dv;                   // pre-scale for the NEXT aggregation
    outp[(size_t)v * 256 + ch] = f2bf(val);
  }
}

// ---------------- launch ----------------
extern "C" void kernel_launch(void* const* d_in, const int* in_sizes, int n_in,
                              void* d_out, int out_size, void* d_ws, size_t ws_size,
                              hipStream_t stream) {
  const float* x   = (const float*)d_in[0];
  const int*   ei  = (const int*)d_in[1];
  const float* W1  = (const float*)d_in[2];
  const float* b1  = (const float*)d_in[3];
  const float* g1  = (const float*)d_in[4];
  const float* be1 = (const float*)d_in[5];
  const float* m1  = (const float*)d_in[6];
  const float* v1  = (const float*)d_in[7];
  const float* W2  = (const float*)d_in[8];
  const float* b2  = (const float*)d_in[9];
  const float* g2  = (const float*)d_in[10];
  const float* be2 = (const float*)d_in[11];
  const float* m2  = (const float*)d_in[12];
  const float* v2  = (const float*)d_in[13];
  const float* W3  = (const float*)d_in[14];
  const float* b3  = (const float*)d_in[15];

  const int IN = 1280, H = 256, OUT = 500, OUTP = 512;
  int E  = in_sizes[1] / 2;
  int nN = in_sizes[0] / IN;
  const int* srcI = ei;
  const int* dstI = ei + E;

  char* p = (char*)d_ws;
  auto carve = [&](size_t bytes) { char* r = p; p += (bytes + 511) & ~(size_t)511; return r; };
  unsigned short* Wt1 = (unsigned short*)carve((size_t)H * IN * 2);
  unsigned short* Wt2 = (unsigned short*)carve((size_t)H * H * 2);
  unsigned short* Wt3 = (unsigned short*)carve((size_t)OUTP * H * 2);
  unsigned* deg  = (unsigned*)carve((size_t)nN * 4);
  float*    dinv = (float*)carve((size_t)nN * 4);
  unsigned* offs = (unsigned*)carve((size_t)(nN + 1) * 4);
  unsigned* cur  = (unsigned*)carve((size_t)nN * 4);
  unsigned* bsum = (unsigned*)carve(256 * 4);
  unsigned* bpre = (unsigned*)carve(256 * 4);
  unsigned short* ewp = (unsigned short*)carve((size_t)(E + nN) * 2);
  unsigned short* bufA = (unsigned short*)carve((size_t)(nN + 1) * H * 2);  // +1 zero pad row
  unsigned short* bufB = (unsigned short*)carve((size_t)(nN + 1) * H * 2);

  hipMemsetAsync(deg, 0, (size_t)nN * 4, stream);

  int NB = (nN + 255) / 256;
  k_count<<<(E + 255) / 256, 256, 0, stream>>>(dstI, deg, E);
  k_prep2<<<NB, 256, 0, stream>>>(deg, dinv, bsum, nN);
  k_scan_top<<<1, 256, 0, stream>>>(bsum, bpre, NB, offs, nN);
  k_scan_fin<<<NB, 256, 0, stream>>>(deg, bpre, offs, cur, nN);
  k_fill<<<(E + nN + 255) / 256, 256, 0, stream>>>(srcI, dstI, cur, ewp, E, nN);
  k_sortw<<<(nN + 3) / 4, 256, 0, stream>>>(offs, ewp, nN);
  k_wt3<<<(256 * 1280 + 256 * 256 + 512 * 256 + 512 + 255) / 256, 256, 0, stream>>>(
      W1, Wt1, W2, Wt2, W3, Wt3, bufA, bufB, nN);

  int MT = (nN + BM - 1) / BM;          // 391
  int mg = (MT + 7) / 8;                // 49
  int nAgg = (nN + 3) / 4;

  // layer 1:  h1' = (x*W1)*dinv ; act1 = BNReLU(dinv*sum h1' + b1)
  k_gemmF<<<mg * 8 * 2, 256, 0, stream>>>(x, Wt1, bufA, dinv, nN, H, IN, MT, 2);
  k_agg<1, 0><<<nAgg, 256, 0, stream>>>(bufA, ewp, offs, dinv, b1, g1, be1, m1, v1, bufB, nN);
  // layer 2:  h2' = (act1*W2)*dinv ; act2' = BNReLU(dinv*sum h2' + b2)*dinv
  k_gemm<0><<<mg * 8 * 2, 256, 0, stream>>>(bufB, Wt2, bufA, nullptr, dinv, nN, H, H, MT, 2);
  k_agg<1, 1><<<nAgg, 256, 0, stream>>>(bufA, ewp, offs, dinv, b2, g2, be2, m2, v2, bufB, nN);
  // layer 3 (reordered):  agg3 = dinv*sum act2' ; out = agg3*W3 + b3
  k_agg<0, 0><<<nAgg, 256, 0, stream>>>(bufB, ewp, offs, dinv, nullptr, nullptr, nullptr,
                                        nullptr, nullptr, bufA, nN);
  k_gemm<1><<<mg * 8 * 4, 256, 0, stream>>>(bufA, Wt3, d_out, b3, nullptr, nN, OUT, H, MT, 4);
}